// Round 9
// baseline (277.532 us; speedup 1.0000x reference)
//
#include <hip/hip_runtime.h>
#include <hip/hip_fp16.h>
#include <stdint.h>

#define DEVI __device__ __forceinline__

using f16x2 = __attribute__((ext_vector_type(2))) _Float16;
using f16x8 = __attribute__((ext_vector_type(8))) _Float16;
using f32x4 = __attribute__((ext_vector_type(4))) float;
using f32x16 = __attribute__((ext_vector_type(16))) float;
using u32x4 = __attribute__((ext_vector_type(4))) uint32_t;

// global -> LDS direct copy, 16B per lane. LDS dest is wave-uniform base;
// HW writes base + lane*16 (guide m104/m108). Global src is per-lane.
DEVI void gload_lds16(const void* g, void* lds) {
  using GP = const __attribute__((address_space(1))) void*;
  using LP = __attribute__((address_space(3))) void*;
  __builtin_amdgcn_global_load_lds((GP)g, (LP)lds, 16, 0, 0);
}

DEVI uint32_t pack2h(float a, float b) {
  return (uint32_t)__half_as_ushort(__float2half(a)) |
         ((uint32_t)__half_as_ushort(__float2half(b)) << 16);
}

DEVI uint32_t cvtpk(float a, float b) {  // v_cvt_pkrtz_f16_f32
  auto h2 = __builtin_amdgcn_cvt_pkrtz(a, b);
  return __builtin_bit_cast(uint32_t, h2);
}

DEVI void plswap(uint32_t& a, uint32_t& b) {  // v_permlane32_swap_b32 (distinct values only)
  asm volatile("v_permlane32_swap_b32 %0, %1" : "+v"(a), "+v"(b));
}

DEVI float dot2acc(uint32_t w, f16x2 one, float c) {  // v_dot2_f32_f16
  return __builtin_amdgcn_fdot2(__builtin_bit_cast(f16x2, w), one, c, false);
}

DEVI float fmax3(float a, float b, float c) { return fmaxf(fmaxf(a, b), c); }

// ---------------- f32 -> f16 convert (vectorized, G13) ----------------
__global__ __launch_bounds__(256) void cvt_f32_f16(const float* __restrict__ in,
                                                   __half* __restrict__ out, int n8) {
  int i = blockIdx.x * 256 + threadIdx.x;
  if (i >= n8) return;
  float4 a = ((const float4*)in)[i * 2];
  float4 b = ((const float4*)in)[i * 2 + 1];
  uint4 u;
  u.x = pack2h(a.x, a.y);
  u.y = pack2h(a.z, a.w);
  u.z = pack2h(b.x, b.y);
  u.w = pack2h(b.z, b.w);
  ((uint4*)out)[i] = u;
}

// ---------------- cos/sin table for RoPE: tab[n][d] = {cos,sin}(rot[n][d]) ----------------
__global__ __launch_bounds__(256) void build_rot_tab(const float* __restrict__ rot,
                                                     float2* __restrict__ tab) {
  int i = blockIdx.x * 256 + threadIdx.x;  // 131072 entries
  float s, c;
  __sincosf(rot[i], &s, &c);
  tab[i] = make_float2(c, s);
}

// ---------------- GEMM: C[M][N] = A[M][K] * B[N][K]^T, f16 in, f32 acc ----------------
// 128x128 tile, BK=32, 4 waves (2x2), 16x16x32 f16 MFMA.
// R9: double-buffered prefetch (proven R8-attn loop shape): STAGE(next buf)
// async, compute(cur buf), one __syncthreads per K-step (drains vmcnt + fences;
// reads-before-barrier / writes-after-barrier discipline keeps it race-free).
DEVI void store_c(__half* p, float v) { *p = __float2half(v); }
DEVI void store_c(float* p, float v) { *p = v; }

template <typename OT>
__global__ __launch_bounds__(256) void gemm_bt(const __half* __restrict__ A,
                                               const __half* __restrict__ B,
                                               OT* __restrict__ C, int M, int N, int K) {
  __shared__ __half As[2][128 * 32];
  __shared__ __half Bs[2][128 * 32];
  const int tid = threadIdx.x;
  const int w = tid >> 6, l = tid & 63;
  const int wm = w >> 1, wn = w & 1;
  const int m16 = l & 15, g = l >> 4;
  const int row0 = blockIdx.y * 128, col0 = blockIdx.x * 128;

  const int srow = l >> 2;
  const int ks = ((l & 3) ^ (srow & 3)) * 8;  // f16 elements

  auto STAGE = [&](int buf, int kt) {
#pragma unroll
    for (int i = 0; i < 2; ++i) {
      int c = w * 2 + i;
      int r = c * 16 + srow;
      gload_lds16(A + (size_t)(row0 + r) * K + kt + ks, (char*)As[buf] + c * 1024);
      gload_lds16(B + (size_t)(col0 + r) * K + kt + ks, (char*)Bs[buf] + c * 1024);
    }
  };

  f32x4 acc[4][4] = {};

  const int nk = K >> 5;
  STAGE(0, 0);
  __syncthreads();

  for (int kt = 0; kt < nk; ++kt) {
    const int buf = kt & 1;
    if (kt + 1 < nk) STAGE(buf ^ 1, (kt + 1) * 32);  // prefetch overlaps compute

    f16x8 aF[4], bF[4];
#pragma unroll
    for (int mi = 0; mi < 4; ++mi) {
      int r = wm * 64 + mi * 16 + m16;
      aF[mi] = *(const f16x8*)((const char*)As[buf] + r * 64 + ((g << 4) ^ ((r & 3) << 4)));
    }
#pragma unroll
    for (int ni = 0; ni < 4; ++ni) {
      int r = wn * 64 + ni * 16 + m16;
      bF[ni] = *(const f16x8*)((const char*)Bs[buf] + r * 64 + ((g << 4) ^ ((r & 3) << 4)));
    }
#pragma unroll
    for (int mi = 0; mi < 4; ++mi)
#pragma unroll
      for (int ni = 0; ni < 4; ++ni)
        acc[mi][ni] = __builtin_amdgcn_mfma_f32_16x16x32_f16(aF[mi], bF[ni], acc[mi][ni], 0, 0, 0);

    __syncthreads();  // staging done (vmcnt drained) + all reads of buf done
  }

#pragma unroll
  for (int mi = 0; mi < 4; ++mi)
#pragma unroll
    for (int ni = 0; ni < 4; ++ni)
#pragma unroll
      for (int j = 0; j < 4; ++j) {
        int r = row0 + wm * 64 + mi * 16 + g * 4 + j;
        int cc = col0 + wn * 64 + ni * 16 + m16;
        store_c(&C[(size_t)r * N + cc], acc[mi][ni][j]);
      }
}

// ---------------- RoPE + scatter to per-head layout (table-based) ----------------
// qkv: [8192][3072] f16 (row = b*2048+n, col = s*1024 + h*64 + d)
// outputs: qr/kr [64 bh][2048 n][64 d]; vr TRANSPOSED [64 bh][64 d][2048 n].
// q pre-scaled by log2(e)/8 so attn uses exp2 with no per-element scale.
// cos/sin from precomputed tab (1 MB, L2/L3-hot) instead of 16.8M __sincosf.
__global__ __launch_bounds__(256) void rope_scatter(const __half* __restrict__ qkv,
                                                    const float2* __restrict__ tab,
                                                    __half* __restrict__ qr,
                                                    __half* __restrict__ kr,
                                                    __half* __restrict__ vr) {
  int t = blockIdx.x * 256 + threadIdx.x;  // 3*64*2048 threads
  int s = t >> 17;
  int rem = t & 131071;
  int bh = rem >> 11;
  int n = rem & 2047;
  int b = bh >> 4, h = bh & 15;
  const __half* src = qkv + (size_t)(b * 2048 + n) * 3072 + s * 1024 + h * 64;
  if (s == 2) {
    // transposed store: vr[bh][d][n]; scalar stores, coalesced across lanes
    __half* vdst = vr + ((size_t)bh * 64) * 2048 + n;
#pragma unroll
    for (int c = 0; c < 8; ++c) {
      f16x8 vv = ((const f16x8*)src)[c];
#pragma unroll
      for (int j = 0; j < 8; ++j) vdst[(size_t)(c * 8 + j) * 2048] = vv[j];
    }
    return;
  }
  __half* dst = (s == 0 ? qr : kr) + ((size_t)bh * 2048 + n) * 64;
  const float sc = (s == 0) ? 0.18033688011112042f : 1.0f;  // log2(e)/sqrt(64)
  const float2* tp = tab + n * 64;
#pragma unroll
  for (int c = 0; c < 4; ++c) {
    f16x8 lo = ((const f16x8*)src)[c];      // d = 8c .. 8c+7
    f16x8 hi = ((const f16x8*)src)[c + 4];  // d+32
    float ol[8], oh[8];
#pragma unroll
    for (int j = 0; j < 8; ++j) {
      int d = c * 8 + j;
      float tl = (float)lo[j], th = (float)hi[j];
      float2 cs0 = tp[d];
      float2 cs1 = tp[d + 32];
      ol[j] = (tl * cs0.x - th * cs0.y) * sc;
      oh[j] = (th * cs1.x + tl * cs1.y) * sc;
    }
    uint4 ulo, uhi;
    ulo.x = pack2h(ol[0], ol[1]); ulo.y = pack2h(ol[2], ol[3]);
    ulo.z = pack2h(ol[4], ol[5]); ulo.w = pack2h(ol[6], ol[7]);
    uhi.x = pack2h(oh[0], oh[1]); uhi.y = pack2h(oh[2], oh[3]);
    uhi.z = pack2h(oh[4], oh[5]); uhi.w = pack2h(oh[6], oh[7]);
    ((uint4*)dst)[c] = ulo;
    ((uint4*)dst)[c + 4] = uhi;
  }
}

// ---------------- Flash attention fwd, swapped-QK 32x32 (UNCHANGED from R8) ----------------
__global__ __launch_bounds__(256, 2) void attn_fwd(const __half* __restrict__ qr,
                                                   const __half* __restrict__ kr,
                                                   const __half* __restrict__ vr,
                                                   __half* __restrict__ out) {
  __shared__ __half K2[2 * 128 * 64];  // 32 KB
  __shared__ __half V2[2 * 64 * 128];  // 32 KB

  int bid = blockIdx.x;
  bid = (bid & 7) * 128 + (bid >> 3);  // XCD swizzle: same-head blocks share an XCD L2
  const int bh = bid >> 4;
  const int q0 = (bid & 15) * 128;
  const int tid = threadIdx.x;
  const int w = tid >> 6, l = tid & 63;
  const int q = l & 31, hi = l >> 5;
  const size_t headoff = (size_t)bh * 2048 * 64;

  // Q B-frags: Q[q0+w*32+q][c*16 + hi*8 .. +7], c=0..3 (held all block)
  f16x8 qB[4];
  {
    const __half* qp = qr + headoff + (size_t)(q0 + w * 32 + q) * 64 + hi * 8;
#pragma unroll
    for (int c = 0; c < 4; ++c) qB[c] = *(const f16x8*)(qp + c * 16);
  }

  // hoisted lane-invariant LDS read offsets
  int kf[4];  // K A-frag: byte = Kb + kvb*4096 + kf[c]
#pragma unroll
  for (int c = 0; c < 4; ++c)
    kf[c] = q * 128 + 16 * (hi ^ (q & 1)) + 32 * (c ^ ((q >> 1) & 3));
  // V B-frag: byte = Vb + (kvb>>1)*8192 + (vbase ^ (kvb&1)<<6 [^32 hi16]) [+4096 d1]
  const int vbase = q * 128 + ((hi ^ (q & 7)) << 4);

  // staging coords
  const int krow_l = l >> 3, kslot = l & 7;
  const __half* kb = kr + headoff;
  const __half* vb = vr + (size_t)bh * 64 * 2048;

  auto STAGE = [&](int buf, int kv0) {
#pragma unroll
    for (int i = 0; i < 4; ++i) {  // K [128 kv][64 d], slot ^= kv&7
      int c = w * 4 + i;
      int row = c * 8 + krow_l;
      gload_lds16(kb + (size_t)(kv0 + row) * 64 + ((kslot ^ (row & 7)) * 8),
                  (char*)K2 + buf * 16384 + c * 1024);
    }
#pragma unroll
    for (int i = 0; i < 4; ++i) {  // V [2 kvh][64 d][64 kv], slot ^= d&7
      int c = w * 4 + i;
      int d = (c & 7) * 8 + (l >> 3);
      gload_lds16(vb + (size_t)d * 2048 + kv0 + (c >> 3) * 64 + (((l & 7) ^ (l >> 3)) * 8),
                  (char*)V2 + buf * 16384 + c * 1024);
    }
  };

  const f16x2 one2 = {(_Float16)1.f, (_Float16)1.f};
  f32x16 o0 = {}, o1 = {};  // O[q-rows][d0=q / d1=q+32]
  float mreg = -1e30f, lreg = 0.f;

  STAGE(0, 0);
  __syncthreads();

  for (int t = 0; t < 16; ++t) {
    const int buf = t & 1;
    if (t < 15) STAGE(buf ^ 1, (t + 1) * 128);  // prefetch next tile (overlaps compute)

    const char* Kb = (const char*)K2 + buf * 16384;
    const char* Vb = (const char*)V2 + buf * 16384;
#pragma unroll
    for (int kvb = 0; kvb < 4; ++kvb) {
      // ---- S^T[kv 32][q 32] = K * Q^T
      f32x16 s = {};
      __builtin_amdgcn_s_setprio(1);
#pragma unroll
      for (int c = 0; c < 4; ++c) {
        f16x8 kA = *(const f16x8*)(Kb + kvb * 4096 + kf[c]);
        s = __builtin_amdgcn_mfma_f32_32x32x16_f16(kA, qB[c], s, 0, 0, 0);
      }
      __builtin_amdgcn_s_setprio(0);

      // ---- in-register online softmax (lane owns q-col l&31, 16 kv rows)
      float mt = fmax3(s[0], s[1], s[2]);
      mt = fmax3(mt, s[3], s[4]);
      mt = fmax3(mt, s[5], s[6]);
      mt = fmax3(mt, s[7], s[8]);
      mt = fmax3(mt, s[9], s[10]);
      mt = fmax3(mt, s[11], s[12]);
      mt = fmax3(mt, s[13], s[14]);
      mt = fmaxf(mt, s[15]);
      mt = fmaxf(mt, __shfl_xor(mt, 32));
      if (__any(mt - mreg > 8.f)) {  // defer-max (T13)
        float mnew = fmaxf(mreg, mt);
        float alpha = __builtin_amdgcn_exp2f(mreg - mnew);
        lreg *= alpha;
        o0 *= alpha;
        o1 *= alpha;
        mreg = mnew;
      }
      uint32_t W[8];
      float rs = 0.f;
#pragma unroll
      for (int i2 = 0; i2 < 8; ++i2) {  // exp2 + pack + fused row-sum (fdot2)
        float e0 = __builtin_amdgcn_exp2f(s[2 * i2] - mreg);
        float e1 = __builtin_amdgcn_exp2f(s[2 * i2 + 1] - mreg);
        W[i2] = cvtpk(e0, e1);
        rs = dot2acc(W[i2], one2, rs);
      }
      rs += __shfl_xor(rs, 32);
      lreg += rs;

      // ---- P-frag redistribution: 4 permlane32_swap (proven)
      plswap(W[0], W[2]);
      plswap(W[1], W[3]);
      plswap(W[4], W[6]);
      plswap(W[5], W[7]);
      u32x4 f0 = {W[0], W[1], W[2], W[3]};
      u32x4 f1 = {W[4], W[5], W[6], W[7]};
      f16x8 pA0 = __builtin_bit_cast(f16x8, f0);  // kv kvb*32 + 0..15
      f16x8 pA1 = __builtin_bit_cast(f16x8, f1);  // kv kvb*32 + 16..31

      // ---- PV: O += P * V   (V reads from 128B-row layout)
      const char* Vk = Vb + (kvb >> 1) * 8192;
      const int vx = vbase ^ ((kvb & 1) << 6);   // kv lo-16 slot
      const int vx2 = vx ^ 32;                   // kv hi-16 slot
      f16x8 v00 = *(const f16x8*)(Vk + vx);
      f16x8 v01 = *(const f16x8*)(Vk + vx + 4096);
      f16x8 v10 = *(const f16x8*)(Vk + vx2);
      f16x8 v11 = *(const f16x8*)(Vk + vx2 + 4096);
      __builtin_amdgcn_s_setprio(1);
      o0 = __builtin_amdgcn_mfma_f32_32x32x16_f16(pA0, v00, o0, 0, 0, 0);
      o1 = __builtin_amdgcn_mfma_f32_32x32x16_f16(pA0, v01, o1, 0, 0, 0);
      o0 = __builtin_amdgcn_mfma_f32_32x32x16_f16(pA1, v10, o0, 0, 0, 0);
      o1 = __builtin_amdgcn_mfma_f32_32x32x16_f16(pA1, v11, o1, 0, 0, 0);
      __builtin_amdgcn_s_setprio(0);
    }

    __syncthreads();  // fence + barrier + counter drain: next tile fully in LDS
  }

  // ---- epilogue: O reg r holds q-row (r&3)+8*(r>>2)+4*hi, d-col q (+0/32)
  const int b = bh >> 4, hh = bh & 15;
  float invl = 1.0f / lreg;
#pragma unroll
  for (int r = 0; r < 16; ++r) {
    int qrow = (r & 3) + 8 * (r >> 2) + 4 * hi;
    float inv = __shfl(invl, qrow);
    __half* orow = out + (size_t)(b * 2048 + q0 + w * 32 + qrow) * 1024 + hh * 64;
    orow[q] = __float2half(o0[r] * inv);
    orow[32 + q] = __float2half(o1[r] * inv);
  }
}

// ---------------- launch ----------------
extern "C" void kernel_launch(void* const* d_in, const int* in_sizes, int n_in,
                              void* d_out, int out_size, void* d_ws, size_t ws_size,
                              hipStream_t stream) {
  const float* x    = (const float*)d_in[0];  // [4,2048,1024]
  const float* rot  = (const float*)d_in[1];  // [2048,64]
  const float* wqkv = (const float*)d_in[2];  // [3072,1024]
  const float* wout = (const float*)d_in[3];  // [1024,1024]
  float* out = (float*)d_out;
  char* ws = (char*)d_ws;

  __half* xb    = (__half*)(ws + 0);               // 16 MB (reused as qr)
  __half* wqkvb = (__half*)(ws + (16ull << 20));   // 6 MB (dead after gemm1 -> reused as tab)
  __half* woutb = (__half*)(ws + (22ull << 20));   // 2 MB
  __half* qkv   = (__half*)(ws + (24ull << 20));   // 48 MB (reused as attn_out)
  __half* kr    = (__half*)(ws + (72ull << 20));   // 16 MB
  __half* vr    = (__half*)(ws + (88ull << 20));   // 16 MB (TRANSPOSED [bh][d][n])
  __half* qr    = xb;
  __half* ao    = qkv;
  float2* tab   = (float2*)wqkvb;                  // 1 MB, built after gemm1

  cvt_f32_f16<<<4096, 256, 0, stream>>>(x, xb, 1048576);
  cvt_f32_f16<<<1536, 256, 0, stream>>>(wqkv, wqkvb, 393216);
  cvt_f32_f16<<<512, 256, 0, stream>>>(wout, woutb, 131072);
  // qkv = xb @ wqkvb^T   [8192,3072]
  gemm_bt<__half><<<dim3(24, 64), 256, 0, stream>>>(xb, wqkvb, qkv, 8192, 3072, 1024);
  build_rot_tab<<<512, 256, 0, stream>>>(rot, tab);  // wqkvb dead from here
  rope_scatter<<<1536, 256, 0, stream>>>(qkv, tab, qr, kr, vr);
  attn_fwd<<<1024, 256, 0, stream>>>(qr, kr, vr, ao);
  // out = ao @ woutb^T   [8192,1024] f32
  gemm_bt<float><<<dim3(8, 64), 256, 0, stream>>>(ao, woutb, out, 8192, 1024, 1024);
}

// Round 10
// 262.919 us; speedup vs baseline: 1.0556x; 1.0556x over previous
//
#include <hip/hip_runtime.h>
#include <hip/hip_fp16.h>
#include <stdint.h>

#define DEVI __device__ __forceinline__

using f16x2 = __attribute__((ext_vector_type(2))) _Float16;
using f16x8 = __attribute__((ext_vector_type(8))) _Float16;
using f32x4 = __attribute__((ext_vector_type(4))) float;
using f32x16 = __attribute__((ext_vector_type(16))) float;
using u32x4 = __attribute__((ext_vector_type(4))) uint32_t;

// global -> LDS direct copy, 16B per lane. LDS dest is wave-uniform base;
// HW writes base + lane*16 (guide m104/m108). Global src is per-lane.
DEVI void gload_lds16(const void* g, void* lds) {
  using GP = const __attribute__((address_space(1))) void*;
  using LP = __attribute__((address_space(3))) void*;
  __builtin_amdgcn_global_load_lds((GP)g, (LP)lds, 16, 0, 0);
}

DEVI uint32_t pack2h(float a, float b) {
  return (uint32_t)__half_as_ushort(__float2half(a)) |
         ((uint32_t)__half_as_ushort(__float2half(b)) << 16);
}

DEVI uint32_t cvtpk(float a, float b) {  // v_cvt_pkrtz_f16_f32
  auto h2 = __builtin_amdgcn_cvt_pkrtz(a, b);
  return __builtin_bit_cast(uint32_t, h2);
}

DEVI void plswap(uint32_t& a, uint32_t& b) {  // v_permlane32_swap_b32 (distinct values only)
  asm volatile("v_permlane32_swap_b32 %0, %1" : "+v"(a), "+v"(b));
}

DEVI float dot2acc(uint32_t w, f16x2 one, float c) {  // v_dot2_f32_f16
  return __builtin_amdgcn_fdot2(__builtin_bit_cast(f16x2, w), one, c, false);
}

DEVI float fmax3(float a, float b, float c) { return fmaxf(fmaxf(a, b), c); }

// ---------------- f32 -> f16 convert (vectorized, G13) ----------------
__global__ __launch_bounds__(256) void cvt_f32_f16(const float* __restrict__ in,
                                                   __half* __restrict__ out, int n8) {
  int i = blockIdx.x * 256 + threadIdx.x;
  if (i >= n8) return;
  float4 a = ((const float4*)in)[i * 2];
  float4 b = ((const float4*)in)[i * 2 + 1];
  uint4 u;
  u.x = pack2h(a.x, a.y);
  u.y = pack2h(a.z, a.w);
  u.z = pack2h(b.x, b.y);
  u.w = pack2h(b.z, b.w);
  ((uint4*)out)[i] = u;
}

// ---------------- GEMM: C[M][N] = A[M][K] * B[N][K]^T, f16 in, f32 acc ----------------
// 128x128 tile, BK=32, 4 waves (2x2), 16x16x32 f16 MFMA. R8's proven
// single-buffer version (R9's dbuf halved blocks/CU -> net regression, reverted).
DEVI void store_c(__half* p, float v) { *p = __float2half(v); }
DEVI void store_c(float* p, float v) { *p = v; }

template <typename OT>
__global__ __launch_bounds__(256) void gemm_bt(const __half* __restrict__ A,
                                               const __half* __restrict__ B,
                                               OT* __restrict__ C, int M, int N, int K) {
  __shared__ __half As[128 * 32];
  __shared__ __half Bs[128 * 32];
  const int tid = threadIdx.x;
  const int w = tid >> 6, l = tid & 63;
  const int wm = w >> 1, wn = w & 1;
  const int m16 = l & 15, g = l >> 4;
  const int row0 = blockIdx.y * 128, col0 = blockIdx.x * 128;

  const int srow = l >> 2;
  const int ks = ((l & 3) ^ (srow & 3)) * 8;  // f16 elements

  f32x4 acc[4][4] = {};

  for (int kt = 0; kt < K; kt += 32) {
    __syncthreads();
#pragma unroll
    for (int i = 0; i < 2; ++i) {
      int c = w * 2 + i;
      int r = c * 16 + srow;
      gload_lds16(A + (size_t)(row0 + r) * K + kt + ks, (char*)As + c * 1024);
      gload_lds16(B + (size_t)(col0 + r) * K + kt + ks, (char*)Bs + c * 1024);
    }
    __syncthreads();
    f16x8 aF[4], bF[4];
#pragma unroll
    for (int mi = 0; mi < 4; ++mi) {
      int r = wm * 64 + mi * 16 + m16;
      aF[mi] = *(const f16x8*)((const char*)As + r * 64 + ((g << 4) ^ ((r & 3) << 4)));
    }
#pragma unroll
    for (int ni = 0; ni < 4; ++ni) {
      int r = wn * 64 + ni * 16 + m16;
      bF[ni] = *(const f16x8*)((const char*)Bs + r * 64 + ((g << 4) ^ ((r & 3) << 4)));
    }
#pragma unroll
    for (int mi = 0; mi < 4; ++mi)
#pragma unroll
      for (int ni = 0; ni < 4; ++ni)
        acc[mi][ni] = __builtin_amdgcn_mfma_f32_16x16x32_f16(aF[mi], bF[ni], acc[mi][ni], 0, 0, 0);
  }

#pragma unroll
  for (int mi = 0; mi < 4; ++mi)
#pragma unroll
    for (int ni = 0; ni < 4; ++ni)
#pragma unroll
      for (int j = 0; j < 4; ++j) {
        int r = row0 + wm * 64 + mi * 16 + g * 4 + j;
        int cc = col0 + wn * 64 + ni * 16 + m16;
        store_c(&C[(size_t)r * N + cc], acc[mi][ni][j]);
      }
}

// ---------------- RoPE + scatter to per-head layout ----------------
// R8's proven __sincosf version (R9's table had uncoalesced 512B-stride reads).
__global__ __launch_bounds__(256) void rope_scatter(const __half* __restrict__ qkv,
                                                    const float* __restrict__ rot,
                                                    __half* __restrict__ qr,
                                                    __half* __restrict__ kr,
                                                    __half* __restrict__ vr) {
  int t = blockIdx.x * 256 + threadIdx.x;  // 3*64*2048 threads
  int s = t >> 17;
  int rem = t & 131071;
  int bh = rem >> 11;
  int n = rem & 2047;
  int b = bh >> 4, h = bh & 15;
  const __half* src = qkv + (size_t)(b * 2048 + n) * 3072 + s * 1024 + h * 64;
  if (s == 2) {
    // transposed store: vr[bh][d][n]; scalar stores, coalesced across lanes
    __half* vdst = vr + ((size_t)bh * 64) * 2048 + n;
#pragma unroll
    for (int c = 0; c < 8; ++c) {
      f16x8 vv = ((const f16x8*)src)[c];
#pragma unroll
      for (int j = 0; j < 8; ++j) vdst[(size_t)(c * 8 + j) * 2048] = vv[j];
    }
    return;
  }
  __half* dst = (s == 0 ? qr : kr) + ((size_t)bh * 2048 + n) * 64;
  const float sc = (s == 0) ? 0.18033688011112042f : 1.0f;  // log2(e)/sqrt(64)
  const float* rp = rot + n * 64;
#pragma unroll
  for (int c = 0; c < 4; ++c) {
    f16x8 lo = ((const f16x8*)src)[c];      // d = 8c .. 8c+7
    f16x8 hi = ((const f16x8*)src)[c + 4];  // d+32
    float ol[8], oh[8];
#pragma unroll
    for (int j = 0; j < 8; ++j) {
      int d = c * 8 + j;
      float tl = (float)lo[j], th = (float)hi[j];
      float s0, c0, s1, c1;
      __sincosf(rp[d], &s0, &c0);
      __sincosf(rp[d + 32], &s1, &c1);
      ol[j] = (tl * c0 - th * s0) * sc;
      oh[j] = (th * c1 + tl * s1) * sc;
    }
    uint4 ulo, uhi;
    ulo.x = pack2h(ol[0], ol[1]); ulo.y = pack2h(ol[2], ol[3]);
    ulo.z = pack2h(ol[4], ol[5]); ulo.w = pack2h(ol[6], ol[7]);
    uhi.x = pack2h(oh[0], oh[1]); uhi.y = pack2h(oh[2], oh[3]);
    uhi.z = pack2h(oh[4], oh[5]); uhi.w = pack2h(oh[6], oh[7]);
    ((uint4*)dst)[c] = ulo;
    ((uint4*)dst)[c + 4] = uhi;
  }
}

// ---------------- Flash attention fwd, swapped-QK 32x32 ----------------
// R10 delta vs R8 (math bit-identical): KVBLK 128 -> 64, dbuf kept.
// LDS 64 KB -> 32 KB => blocks/CU 2 -> 4-5 (Occupancy ~20% -> ~40%); the
// per-tile __syncthreads vmcnt-drain now overlaps other blocks' compute.
// K tile [64 kv][64 d], slot ^= kv&7. V tile [64 d][64 kv] (128B rows),
// slot ^= d&7 — same formulas as R8 with the kvh dimension degenerate.
__global__ __launch_bounds__(256, 4) void attn_fwd(const __half* __restrict__ qr,
                                                   const __half* __restrict__ kr,
                                                   const __half* __restrict__ vr,
                                                   __half* __restrict__ out) {
  __shared__ __half K2[2 * 64 * 64];  // 16 KB
  __shared__ __half V2[2 * 64 * 64];  // 16 KB

  int bid = blockIdx.x;
  bid = (bid & 7) * 128 + (bid >> 3);  // XCD swizzle: same-head blocks share an XCD L2
  const int bh = bid >> 4;
  const int q0 = (bid & 15) * 128;
  const int tid = threadIdx.x;
  const int w = tid >> 6, l = tid & 63;
  const int q = l & 31, hi = l >> 5;
  const size_t headoff = (size_t)bh * 2048 * 64;

  // Q B-frags: Q[q0+w*32+q][c*16 + hi*8 .. +7], c=0..3 (held all block)
  f16x8 qB[4];
  {
    const __half* qp = qr + headoff + (size_t)(q0 + w * 32 + q) * 64 + hi * 8;
#pragma unroll
    for (int c = 0; c < 4; ++c) qB[c] = *(const f16x8*)(qp + c * 16);
  }

  // hoisted lane-invariant LDS read offsets
  int kf[4];  // K A-frag: byte = Kb + kvb*4096 + kf[c]   (kvb in {0,1})
#pragma unroll
  for (int c = 0; c < 4; ++c)
    kf[c] = q * 128 + 16 * (hi ^ (q & 1)) + 32 * (c ^ ((q >> 1) & 3));
  // V B-frag: byte = Vb + (vbase ^ (kvb<<6) [^32 hi16]) [+4096 for d1]
  const int vbase = q * 128 + ((hi ^ (q & 7)) << 4);

  // staging coords
  const int krow_l = l >> 3, kslot = l & 7;
  const __half* kb = kr + headoff;
  const __half* vb = vr + (size_t)bh * 64 * 2048;

  auto STAGE = [&](int buf, int kv0) {
#pragma unroll
    for (int i = 0; i < 2; ++i) {  // K [64 kv][64 d], slot ^= kv&7
      int c = w * 2 + i;
      int row = c * 8 + krow_l;
      gload_lds16(kb + (size_t)(kv0 + row) * 64 + ((kslot ^ (row & 7)) * 8),
                  (char*)K2 + buf * 8192 + c * 1024);
    }
#pragma unroll
    for (int i = 0; i < 2; ++i) {  // V [64 d][64 kv], slot ^= d&7
      int c = w * 2 + i;
      int d = c * 8 + (l >> 3);
      gload_lds16(vb + (size_t)d * 2048 + kv0 + (((l & 7) ^ (l >> 3)) * 8),
                  (char*)V2 + buf * 8192 + c * 1024);
    }
  };

  const f16x2 one2 = {(_Float16)1.f, (_Float16)1.f};
  f32x16 o0 = {}, o1 = {};  // O[q-rows][d0=q / d1=q+32]
  float mreg = -1e30f, lreg = 0.f;

  STAGE(0, 0);
  __syncthreads();

  for (int t = 0; t < 32; ++t) {
    const int buf = t & 1;
    if (t < 31) STAGE(buf ^ 1, (t + 1) * 64);  // prefetch next tile (overlaps compute)

    const char* Kb = (const char*)K2 + buf * 8192;
    const char* Vb = (const char*)V2 + buf * 8192;
#pragma unroll
    for (int kvb = 0; kvb < 2; ++kvb) {
      // ---- S^T[kv 32][q 32] = K * Q^T
      f32x16 s = {};
      __builtin_amdgcn_s_setprio(1);
#pragma unroll
      for (int c = 0; c < 4; ++c) {
        f16x8 kA = *(const f16x8*)(Kb + kvb * 4096 + kf[c]);
        s = __builtin_amdgcn_mfma_f32_32x32x16_f16(kA, qB[c], s, 0, 0, 0);
      }
      __builtin_amdgcn_s_setprio(0);

      // ---- in-register online softmax (lane owns q-col l&31, 16 kv rows)
      float mt = fmax3(s[0], s[1], s[2]);
      mt = fmax3(mt, s[3], s[4]);
      mt = fmax3(mt, s[5], s[6]);
      mt = fmax3(mt, s[7], s[8]);
      mt = fmax3(mt, s[9], s[10]);
      mt = fmax3(mt, s[11], s[12]);
      mt = fmax3(mt, s[13], s[14]);
      mt = fmaxf(mt, s[15]);
      mt = fmaxf(mt, __shfl_xor(mt, 32));
      if (__any(mt - mreg > 8.f)) {  // defer-max (T13)
        float mnew = fmaxf(mreg, mt);
        float alpha = __builtin_amdgcn_exp2f(mreg - mnew);
        lreg *= alpha;
        o0 *= alpha;
        o1 *= alpha;
        mreg = mnew;
      }
      uint32_t W[8];
      float rs = 0.f;
#pragma unroll
      for (int i2 = 0; i2 < 8; ++i2) {  // exp2 + pack + fused row-sum (fdot2)
        float e0 = __builtin_amdgcn_exp2f(s[2 * i2] - mreg);
        float e1 = __builtin_amdgcn_exp2f(s[2 * i2 + 1] - mreg);
        W[i2] = cvtpk(e0, e1);
        rs = dot2acc(W[i2], one2, rs);
      }
      rs += __shfl_xor(rs, 32);
      lreg += rs;

      // ---- P-frag redistribution: 4 permlane32_swap (proven)
      plswap(W[0], W[2]);
      plswap(W[1], W[3]);
      plswap(W[4], W[6]);
      plswap(W[5], W[7]);
      u32x4 f0 = {W[0], W[1], W[2], W[3]};
      u32x4 f1 = {W[4], W[5], W[6], W[7]};
      f16x8 pA0 = __builtin_bit_cast(f16x8, f0);  // kv kvb*32 + 0..15
      f16x8 pA1 = __builtin_bit_cast(f16x8, f1);  // kv kvb*32 + 16..31

      // ---- PV: O += P * V   (V reads from 128B-row layout)
      const int vx = vbase ^ (kvb << 6);   // kv lo-16 slot
      const int vx2 = vx ^ 32;             // kv hi-16 slot
      f16x8 v00 = *(const f16x8*)(Vb + vx);
      f16x8 v01 = *(const f16x8*)(Vb + vx + 4096);
      f16x8 v10 = *(const f16x8*)(Vb + vx2);
      f16x8 v11 = *(const f16x8*)(Vb + vx2 + 4096);
      __builtin_amdgcn_s_setprio(1);
      o0 = __builtin_amdgcn_mfma_f32_32x32x16_f16(pA0, v00, o0, 0, 0, 0);
      o1 = __builtin_amdgcn_mfma_f32_32x32x16_f16(pA0, v01, o1, 0, 0, 0);
      o0 = __builtin_amdgcn_mfma_f32_32x32x16_f16(pA1, v10, o0, 0, 0, 0);
      o1 = __builtin_amdgcn_mfma_f32_32x32x16_f16(pA1, v11, o1, 0, 0, 0);
      __builtin_amdgcn_s_setprio(0);
    }

    __syncthreads();  // fence + barrier + counter drain: next tile fully in LDS
  }

  // ---- epilogue: O reg r holds q-row (r&3)+8*(r>>2)+4*hi, d-col q (+0/32)
  const int b = bh >> 4, hh = bh & 15;
  float invl = 1.0f / lreg;
#pragma unroll
  for (int r = 0; r < 16; ++r) {
    int qrow = (r & 3) + 8 * (r >> 2) + 4 * hi;
    float inv = __shfl(invl, qrow);
    __half* orow = out + (size_t)(b * 2048 + q0 + w * 32 + qrow) * 1024 + hh * 64;
    orow[q] = __float2half(o0[r] * inv);
    orow[32 + q] = __float2half(o1[r] * inv);
  }
}

// ---------------- launch ----------------
extern "C" void kernel_launch(void* const* d_in, const int* in_sizes, int n_in,
                              void* d_out, int out_size, void* d_ws, size_t ws_size,
                              hipStream_t stream) {
  const float* x    = (const float*)d_in[0];  // [4,2048,1024]
  const float* rot  = (const float*)d_in[1];  // [2048,64]
  const float* wqkv = (const float*)d_in[2];  // [3072,1024]
  const float* wout = (const float*)d_in[3];  // [1024,1024]
  float* out = (float*)d_out;
  char* ws = (char*)d_ws;

  __half* xb    = (__half*)(ws + 0);               // 16 MB (reused as qr)
  __half* wqkvb = (__half*)(ws + (16ull << 20));   // 6 MB
  __half* woutb = (__half*)(ws + (22ull << 20));   // 2 MB
  __half* qkv   = (__half*)(ws + (24ull << 20));   // 48 MB (reused as attn_out)
  __half* kr    = (__half*)(ws + (72ull << 20));   // 16 MB
  __half* vr    = (__half*)(ws + (88ull << 20));   // 16 MB (TRANSPOSED [bh][d][n])
  __half* qr    = xb;
  __half* ao    = qkv;

  cvt_f32_f16<<<4096, 256, 0, stream>>>(x, xb, 1048576);
  cvt_f32_f16<<<1536, 256, 0, stream>>>(wqkv, wqkvb, 393216);
  cvt_f32_f16<<<512, 256, 0, stream>>>(wout, woutb, 131072);
  // qkv = xb @ wqkvb^T   [8192,3072]
  gemm_bt<__half><<<dim3(24, 64), 256, 0, stream>>>(xb, wqkvb, qkv, 8192, 3072, 1024);
  rope_scatter<<<1536, 256, 0, stream>>>(qkv, rot, qr, kr, vr);
  attn_fwd<<<1024, 256, 0, stream>>>(qr, kr, vr, ao);
  // out = ao @ woutb^T   [8192,1024] f32
  gemm_bt<float><<<dim3(8, 64), 256, 0, stream>>>(ao, woutb, out, 8192, 1024, 1024);
}

// Round 11
// 250.327 us; speedup vs baseline: 1.1087x; 1.0503x over previous
//
#include <hip/hip_runtime.h>
#include <hip/hip_fp16.h>
#include <stdint.h>

#define DEVI __device__ __forceinline__

using f16x2 = __attribute__((ext_vector_type(2))) _Float16;
using f16x8 = __attribute__((ext_vector_type(8))) _Float16;
using f32x4 = __attribute__((ext_vector_type(4))) float;
using f32x16 = __attribute__((ext_vector_type(16))) float;
using u32x4 = __attribute__((ext_vector_type(4))) uint32_t;

// global -> LDS direct copy, 16B per lane. LDS dest is wave-uniform base;
// HW writes base + lane*16 (guide m104/m108). Global src is per-lane.
DEVI void gload_lds16(const void* g, void* lds) {
  using GP = const __attribute__((address_space(1))) void*;
  using LP = __attribute__((address_space(3))) void*;
  __builtin_amdgcn_global_load_lds((GP)g, (LP)lds, 16, 0, 0);
}

DEVI uint32_t pack2h(float a, float b) {
  return (uint32_t)__half_as_ushort(__float2half(a)) |
         ((uint32_t)__half_as_ushort(__float2half(b)) << 16);
}

DEVI uint32_t cvtpk(float a, float b) {  // v_cvt_pkrtz_f16_f32
  auto h2 = __builtin_amdgcn_cvt_pkrtz(a, b);
  return __builtin_bit_cast(uint32_t, h2);
}

DEVI void plswap(uint32_t& a, uint32_t& b) {  // v_permlane32_swap_b32 (distinct values only)
  asm volatile("v_permlane32_swap_b32 %0, %1" : "+v"(a), "+v"(b));
}

DEVI float dot2acc(uint32_t w, f16x2 one, float c) {  // v_dot2_f32_f16
  return __builtin_amdgcn_fdot2(__builtin_bit_cast(f16x2, w), one, c, false);
}

DEVI float fmax3(float a, float b, float c) { return fmaxf(fmaxf(a, b), c); }

// ---------------- f32 -> f16 convert (vectorized, G13) ----------------
__global__ __launch_bounds__(256) void cvt_f32_f16(const float* __restrict__ in,
                                                   __half* __restrict__ out, int n8) {
  int i = blockIdx.x * 256 + threadIdx.x;
  if (i >= n8) return;
  float4 a = ((const float4*)in)[i * 2];
  float4 b = ((const float4*)in)[i * 2 + 1];
  uint4 u;
  u.x = pack2h(a.x, a.y);
  u.y = pack2h(a.z, a.w);
  u.z = pack2h(b.x, b.y);
  u.w = pack2h(b.z, b.w);
  ((uint4*)out)[i] = u;
}

// ---------------- GEMM: C[M][N] = A[M][K] * B[N][K]^T, f16 in, f32 acc ----------------
// 128x128 tile, BK=64 (R11: halves barrier-drain count vs BK=32; 32 KB LDS
// single-buffered keeps ~3 blocks/CU — avoids m132's 64KB occupancy cliff).
// Staging/read swizzle = attn's proven K-tile scheme: 128B rows, 16B slot ^= row&7.
// Read-side: 16 rows x 2 g per 32-lane half -> 4 lanes/quad balanced = conflict-free.
DEVI void store_c(__half* p, float v) { *p = __float2half(v); }
DEVI void store_c(float* p, float v) { *p = v; }

template <typename OT>
__global__ __launch_bounds__(256) void gemm_bt(const __half* __restrict__ A,
                                               const __half* __restrict__ B,
                                               OT* __restrict__ C, int M, int N, int K) {
  __shared__ __half As[128 * 64];  // 16 KB each, 128B rows
  __shared__ __half Bs[128 * 64];
  const int tid = threadIdx.x;
  const int w = tid >> 6, l = tid & 63;
  const int wm = w >> 1, wn = w & 1;
  const int m16 = l & 15, g = l >> 4;
  const int row0 = blockIdx.y * 128, col0 = blockIdx.x * 128;

  // staging: chunk c (1 KB) = rows c*8..c*8+7; lane -> row c*8+(l>>3), slot l&7,
  // source k-slot = slot ^ (row&7)  (row&7 == l>>3)
  const int srow = l >> 3;
  const int ks = ((l & 7) ^ srow) * 8;  // f16 elements

  f32x4 acc[4][4] = {};

  for (int kt = 0; kt < K; kt += 64) {
    __syncthreads();
#pragma unroll
    for (int i = 0; i < 4; ++i) {
      int c = w * 4 + i;
      int r = c * 8 + srow;
      gload_lds16(A + (size_t)(row0 + r) * K + kt + ks, (char*)As + c * 1024);
      gload_lds16(B + (size_t)(col0 + r) * K + kt + ks, (char*)Bs + c * 1024);
    }
    __syncthreads();
#pragma unroll
    for (int kk = 0; kk < 2; ++kk) {  // two K=32 sub-steps; aF/bF reused (8 live frags)
      f16x8 aF[4], bF[4];
#pragma unroll
      for (int mi = 0; mi < 4; ++mi) {
        int r = wm * 64 + mi * 16 + m16;
        aF[mi] = *(const f16x8*)((const char*)As + r * 128 + (((kk * 4 + g) ^ (r & 7)) << 4));
      }
#pragma unroll
      for (int ni = 0; ni < 4; ++ni) {
        int r = wn * 64 + ni * 16 + m16;
        bF[ni] = *(const f16x8*)((const char*)Bs + r * 128 + (((kk * 4 + g) ^ (r & 7)) << 4));
      }
#pragma unroll
      for (int mi = 0; mi < 4; ++mi)
#pragma unroll
        for (int ni = 0; ni < 4; ++ni)
          acc[mi][ni] = __builtin_amdgcn_mfma_f32_16x16x32_f16(aF[mi], bF[ni], acc[mi][ni], 0, 0, 0);
    }
  }

#pragma unroll
  for (int mi = 0; mi < 4; ++mi)
#pragma unroll
    for (int ni = 0; ni < 4; ++ni)
#pragma unroll
      for (int j = 0; j < 4; ++j) {
        int r = row0 + wm * 64 + mi * 16 + g * 4 + j;
        int cc = col0 + wn * 64 + ni * 16 + m16;
        store_c(&C[(size_t)r * N + cc], acc[mi][ni][j]);
      }
}

// ---------------- RoPE + scatter to per-head layout (unchanged, proven) ----------------
__global__ __launch_bounds__(256) void rope_scatter(const __half* __restrict__ qkv,
                                                    const float* __restrict__ rot,
                                                    __half* __restrict__ qr,
                                                    __half* __restrict__ kr,
                                                    __half* __restrict__ vr) {
  int t = blockIdx.x * 256 + threadIdx.x;  // 3*64*2048 threads
  int s = t >> 17;
  int rem = t & 131071;
  int bh = rem >> 11;
  int n = rem & 2047;
  int b = bh >> 4, h = bh & 15;
  const __half* src = qkv + (size_t)(b * 2048 + n) * 3072 + s * 1024 + h * 64;
  if (s == 2) {
    // transposed store: vr[bh][d][n]; scalar stores, coalesced across lanes
    __half* vdst = vr + ((size_t)bh * 64) * 2048 + n;
#pragma unroll
    for (int c = 0; c < 8; ++c) {
      f16x8 vv = ((const f16x8*)src)[c];
#pragma unroll
      for (int j = 0; j < 8; ++j) vdst[(size_t)(c * 8 + j) * 2048] = vv[j];
    }
    return;
  }
  __half* dst = (s == 0 ? qr : kr) + ((size_t)bh * 2048 + n) * 64;
  const float sc = (s == 0) ? 0.18033688011112042f : 1.0f;  // log2(e)/sqrt(64)
  const float* rp = rot + n * 64;
#pragma unroll
  for (int c = 0; c < 4; ++c) {
    f16x8 lo = ((const f16x8*)src)[c];      // d = 8c .. 8c+7
    f16x8 hi = ((const f16x8*)src)[c + 4];  // d+32
    float ol[8], oh[8];
#pragma unroll
    for (int j = 0; j < 8; ++j) {
      int d = c * 8 + j;
      float tl = (float)lo[j], th = (float)hi[j];
      float s0, c0, s1, c1;
      __sincosf(rp[d], &s0, &c0);
      __sincosf(rp[d + 32], &s1, &c1);
      ol[j] = (tl * c0 - th * s0) * sc;
      oh[j] = (th * c1 + tl * s1) * sc;
    }
    uint4 ulo, uhi;
    ulo.x = pack2h(ol[0], ol[1]); ulo.y = pack2h(ol[2], ol[3]);
    ulo.z = pack2h(ol[4], ol[5]); ulo.w = pack2h(ol[6], ol[7]);
    uhi.x = pack2h(oh[0], oh[1]); uhi.y = pack2h(oh[2], oh[3]);
    uhi.z = pack2h(oh[4], oh[5]); uhi.w = pack2h(oh[6], oh[7]);
    ((uint4*)dst)[c] = ulo;
    ((uint4*)dst)[c + 4] = uhi;
  }
}

// ---------------- Flash attention fwd, swapped-QK 32x32 (UNCHANGED from R10) ----------------
__global__ __launch_bounds__(256, 4) void attn_fwd(const __half* __restrict__ qr,
                                                   const __half* __restrict__ kr,
                                                   const __half* __restrict__ vr,
                                                   __half* __restrict__ out) {
  __shared__ __half K2[2 * 64 * 64];  // 16 KB
  __shared__ __half V2[2 * 64 * 64];  // 16 KB

  int bid = blockIdx.x;
  bid = (bid & 7) * 128 + (bid >> 3);  // XCD swizzle: same-head blocks share an XCD L2
  const int bh = bid >> 4;
  const int q0 = (bid & 15) * 128;
  const int tid = threadIdx.x;
  const int w = tid >> 6, l = tid & 63;
  const int q = l & 31, hi = l >> 5;
  const size_t headoff = (size_t)bh * 2048 * 64;

  // Q B-frags: Q[q0+w*32+q][c*16 + hi*8 .. +7], c=0..3 (held all block)
  f16x8 qB[4];
  {
    const __half* qp = qr + headoff + (size_t)(q0 + w * 32 + q) * 64 + hi * 8;
#pragma unroll
    for (int c = 0; c < 4; ++c) qB[c] = *(const f16x8*)(qp + c * 16);
  }

  // hoisted lane-invariant LDS read offsets
  int kf[4];  // K A-frag: byte = Kb + kvb*4096 + kf[c]   (kvb in {0,1})
#pragma unroll
  for (int c = 0; c < 4; ++c)
    kf[c] = q * 128 + 16 * (hi ^ (q & 1)) + 32 * (c ^ ((q >> 1) & 3));
  // V B-frag: byte = Vb + (vbase ^ (kvb<<6) [^32 hi16]) [+4096 for d1]
  const int vbase = q * 128 + ((hi ^ (q & 7)) << 4);

  // staging coords
  const int krow_l = l >> 3, kslot = l & 7;
  const __half* kb = kr + headoff;
  const __half* vb = vr + (size_t)bh * 64 * 2048;

  auto STAGE = [&](int buf, int kv0) {
#pragma unroll
    for (int i = 0; i < 2; ++i) {  // K [64 kv][64 d], slot ^= kv&7
      int c = w * 2 + i;
      int row = c * 8 + krow_l;
      gload_lds16(kb + (size_t)(kv0 + row) * 64 + ((kslot ^ (row & 7)) * 8),
                  (char*)K2 + buf * 8192 + c * 1024);
    }
#pragma unroll
    for (int i = 0; i < 2; ++i) {  // V [64 d][64 kv], slot ^= d&7
      int c = w * 2 + i;
      int d = c * 8 + (l >> 3);
      gload_lds16(vb + (size_t)d * 2048 + kv0 + (((l & 7) ^ (l >> 3)) * 8),
                  (char*)V2 + buf * 8192 + c * 1024);
    }
  };

  const f16x2 one2 = {(_Float16)1.f, (_Float16)1.f};
  f32x16 o0 = {}, o1 = {};  // O[q-rows][d0=q / d1=q+32]
  float mreg = -1e30f, lreg = 0.f;

  STAGE(0, 0);
  __syncthreads();

  for (int t = 0; t < 32; ++t) {
    const int buf = t & 1;
    if (t < 31) STAGE(buf ^ 1, (t + 1) * 64);  // prefetch next tile (overlaps compute)

    const char* Kb = (const char*)K2 + buf * 8192;
    const char* Vb = (const char*)V2 + buf * 8192;
#pragma unroll
    for (int kvb = 0; kvb < 2; ++kvb) {
      // ---- S^T[kv 32][q 32] = K * Q^T
      f32x16 s = {};
      __builtin_amdgcn_s_setprio(1);
#pragma unroll
      for (int c = 0; c < 4; ++c) {
        f16x8 kA = *(const f16x8*)(Kb + kvb * 4096 + kf[c]);
        s = __builtin_amdgcn_mfma_f32_32x32x16_f16(kA, qB[c], s, 0, 0, 0);
      }
      __builtin_amdgcn_s_setprio(0);

      // ---- in-register online softmax (lane owns q-col l&31, 16 kv rows)
      float mt = fmax3(s[0], s[1], s[2]);
      mt = fmax3(mt, s[3], s[4]);
      mt = fmax3(mt, s[5], s[6]);
      mt = fmax3(mt, s[7], s[8]);
      mt = fmax3(mt, s[9], s[10]);
      mt = fmax3(mt, s[11], s[12]);
      mt = fmax3(mt, s[13], s[14]);
      mt = fmaxf(mt, s[15]);
      mt = fmaxf(mt, __shfl_xor(mt, 32));
      if (__any(mt - mreg > 8.f)) {  // defer-max (T13)
        float mnew = fmaxf(mreg, mt);
        float alpha = __builtin_amdgcn_exp2f(mreg - mnew);
        lreg *= alpha;
        o0 *= alpha;
        o1 *= alpha;
        mreg = mnew;
      }
      uint32_t W[8];
      float rs = 0.f;
#pragma unroll
      for (int i2 = 0; i2 < 8; ++i2) {  // exp2 + pack + fused row-sum (fdot2)
        float e0 = __builtin_amdgcn_exp2f(s[2 * i2] - mreg);
        float e1 = __builtin_amdgcn_exp2f(s[2 * i2 + 1] - mreg);
        W[i2] = cvtpk(e0, e1);
        rs = dot2acc(W[i2], one2, rs);
      }
      rs += __shfl_xor(rs, 32);
      lreg += rs;

      // ---- P-frag redistribution: 4 permlane32_swap (proven)
      plswap(W[0], W[2]);
      plswap(W[1], W[3]);
      plswap(W[4], W[6]);
      plswap(W[5], W[7]);
      u32x4 f0 = {W[0], W[1], W[2], W[3]};
      u32x4 f1 = {W[4], W[5], W[6], W[7]};
      f16x8 pA0 = __builtin_bit_cast(f16x8, f0);  // kv kvb*32 + 0..15
      f16x8 pA1 = __builtin_bit_cast(f16x8, f1);  // kv kvb*32 + 16..31

      // ---- PV: O += P * V   (V reads from 128B-row layout)
      const int vx = vbase ^ (kvb << 6);   // kv lo-16 slot
      const int vx2 = vx ^ 32;             // kv hi-16 slot
      f16x8 v00 = *(const f16x8*)(Vb + vx);
      f16x8 v01 = *(const f16x8*)(Vb + vx + 4096);
      f16x8 v10 = *(const f16x8*)(Vb + vx2);
      f16x8 v11 = *(const f16x8*)(Vb + vx2 + 4096);
      __builtin_amdgcn_s_setprio(1);
      o0 = __builtin_amdgcn_mfma_f32_32x32x16_f16(pA0, v00, o0, 0, 0, 0);
      o1 = __builtin_amdgcn_mfma_f32_32x32x16_f16(pA0, v01, o1, 0, 0, 0);
      o0 = __builtin_amdgcn_mfma_f32_32x32x16_f16(pA1, v10, o0, 0, 0, 0);
      o1 = __builtin_amdgcn_mfma_f32_32x32x16_f16(pA1, v11, o1, 0, 0, 0);
      __builtin_amdgcn_s_setprio(0);
    }

    __syncthreads();  // fence + barrier + counter drain: next tile fully in LDS
  }

  // ---- epilogue: O reg r holds q-row (r&3)+8*(r>>2)+4*hi, d-col q (+0/32)
  const int b = bh >> 4, hh = bh & 15;
  float invl = 1.0f / lreg;
#pragma unroll
  for (int r = 0; r < 16; ++r) {
    int qrow = (r & 3) + 8 * (r >> 2) + 4 * hi;
    float inv = __shfl(invl, qrow);
    __half* orow = out + (size_t)(b * 2048 + q0 + w * 32 + qrow) * 1024 + hh * 64;
    orow[q] = __float2half(o0[r] * inv);
    orow[32 + q] = __float2half(o1[r] * inv);
  }
}

// ---------------- launch ----------------
extern "C" void kernel_launch(void* const* d_in, const int* in_sizes, int n_in,
                              void* d_out, int out_size, void* d_ws, size_t ws_size,
                              hipStream_t stream) {
  const float* x    = (const float*)d_in[0];  // [4,2048,1024]
  const float* rot  = (const float*)d_in[1];  // [2048,64]
  const float* wqkv = (const float*)d_in[2];  // [3072,1024]
  const float* wout = (const float*)d_in[3];  // [1024,1024]
  float* out = (float*)d_out;
  char* ws = (char*)d_ws;

  __half* xb    = (__half*)(ws + 0);               // 16 MB (reused as qr)
  __half* wqkvb = (__half*)(ws + (16ull << 20));   // 6 MB
  __half* woutb = (__half*)(ws + (22ull << 20));   // 2 MB
  __half* qkv   = (__half*)(ws + (24ull << 20));   // 48 MB (reused as attn_out)
  __half* kr    = (__half*)(ws + (72ull << 20));   // 16 MB
  __half* vr    = (__half*)(ws + (88ull << 20));   // 16 MB (TRANSPOSED [bh][d][n])
  __half* qr    = xb;
  __half* ao    = qkv;

  cvt_f32_f16<<<4096, 256, 0, stream>>>(x, xb, 1048576);
  cvt_f32_f16<<<1536, 256, 0, stream>>>(wqkv, wqkvb, 393216);
  cvt_f32_f16<<<512, 256, 0, stream>>>(wout, woutb, 131072);
  // qkv = xb @ wqkvb^T   [8192,3072]
  gemm_bt<__half><<<dim3(24, 64), 256, 0, stream>>>(xb, wqkvb, qkv, 8192, 3072, 1024);
  rope_scatter<<<1536, 256, 0, stream>>>(qkv, rot, qr, kr, vr);
  attn_fwd<<<1024, 256, 0, stream>>>(qr, kr, vr, ao);
  // out = ao @ woutb^T   [8192,1024] f32
  gemm_bt<float><<<dim3(8, 64), 256, 0, stream>>>(ao, woutb, out, 8192, 1024, 1024);
}

// Round 12
// 217.618 us; speedup vs baseline: 1.2753x; 1.1503x over previous
//
#include <hip/hip_runtime.h>
#include <hip/hip_fp16.h>
#include <stdint.h>

#define DEVI __device__ __forceinline__

using f16x2 = __attribute__((ext_vector_type(2))) _Float16;
using f16x8 = __attribute__((ext_vector_type(8))) _Float16;
using f32x4 = __attribute__((ext_vector_type(4))) float;
using f32x16 = __attribute__((ext_vector_type(16))) float;
using u32x4 = __attribute__((ext_vector_type(4))) uint32_t;

// global -> LDS direct copy, 16B per lane. LDS dest is wave-uniform base;
// HW writes base + lane*16 (guide m104/m108). Global src is per-lane.
DEVI void gload_lds16(const void* g, void* lds) {
  using GP = const __attribute__((address_space(1))) void*;
  using LP = __attribute__((address_space(3))) void*;
  __builtin_amdgcn_global_load_lds((GP)g, (LP)lds, 16, 0, 0);
}

DEVI uint32_t pack2h(float a, float b) {
  return (uint32_t)__half_as_ushort(__float2half(a)) |
         ((uint32_t)__half_as_ushort(__float2half(b)) << 16);
}

DEVI uint32_t cvtpk(float a, float b) {  // v_cvt_pkrtz_f16_f32
  auto h2 = __builtin_amdgcn_cvt_pkrtz(a, b);
  return __builtin_bit_cast(uint32_t, h2);
}

DEVI void plswap(uint32_t& a, uint32_t& b) {  // v_permlane32_swap_b32 (distinct values only)
  asm volatile("v_permlane32_swap_b32 %0, %1" : "+v"(a), "+v"(b));
}

DEVI float dot2acc(uint32_t w, f16x2 one, float c) {  // v_dot2_f32_f16
  return __builtin_amdgcn_fdot2(__builtin_bit_cast(f16x2, w), one, c, false);
}

DEVI float fmax3(float a, float b, float c) { return fmaxf(fmaxf(a, b), c); }

// ---------------- f32 -> f16 convert (vectorized, G13) ----------------
__global__ __launch_bounds__(256) void cvt_f32_f16(const float* __restrict__ in,
                                                   __half* __restrict__ out, int n8) {
  int i = blockIdx.x * 256 + threadIdx.x;
  if (i >= n8) return;
  float4 a = ((const float4*)in)[i * 2];
  float4 b = ((const float4*)in)[i * 2 + 1];
  uint4 u;
  u.x = pack2h(a.x, a.y);
  u.y = pack2h(a.z, a.w);
  u.z = pack2h(b.x, b.y);
  u.w = pack2h(b.z, b.w);
  ((uint4*)out)[i] = u;
}

// ================= shared GEMM core (128x128 tile, BK=64, proven R11) ==========
// staging swizzle: 128B rows, 16B slot ^= row&7; read: conflict-free per half.
#define GEMM_CORE(A_, B_, K_)                                                           \
  __shared__ __half As[128 * 64];                                                       \
  __shared__ __half Bs[128 * 64];                                                       \
  const int tid = threadIdx.x;                                                          \
  const int w = tid >> 6, l = tid & 63;                                                 \
  const int wm = w >> 1, wn = w & 1;                                                    \
  const int m16 = l & 15, g = l >> 4;                                                   \
  const int row0 = blockIdx.y * 128, col0 = blockIdx.x * 128;                           \
  const int srow = l >> 3;                                                              \
  const int ks = ((l & 7) ^ srow) * 8;                                                  \
  f32x4 acc[4][4] = {};                                                                 \
  for (int kt = 0; kt < (K_); kt += 64) {                                               \
    __syncthreads();                                                                    \
    _Pragma("unroll") for (int i = 0; i < 4; ++i) {                                     \
      int c = w * 4 + i;                                                                \
      int r = c * 8 + srow;                                                             \
      gload_lds16((A_) + (size_t)(row0 + r) * (K_) + kt + ks, (char*)As + c * 1024);    \
      gload_lds16((B_) + (size_t)(col0 + r) * (K_) + kt + ks, (char*)Bs + c * 1024);    \
    }                                                                                   \
    __syncthreads();                                                                    \
    _Pragma("unroll") for (int kk = 0; kk < 2; ++kk) {                                  \
      f16x8 aF[4], bF[4];                                                               \
      _Pragma("unroll") for (int mi = 0; mi < 4; ++mi) {                                \
        int r = wm * 64 + mi * 16 + m16;                                                \
        aF[mi] = *(const f16x8*)((const char*)As + r * 128 + (((kk * 4 + g) ^ (r & 7)) << 4)); \
      }                                                                                 \
      _Pragma("unroll") for (int ni = 0; ni < 4; ++ni) {                                \
        int r = wn * 64 + ni * 16 + m16;                                                \
        bF[ni] = *(const f16x8*)((const char*)Bs + r * 128 + (((kk * 4 + g) ^ (r & 7)) << 4)); \
      }                                                                                 \
      _Pragma("unroll") for (int mi = 0; mi < 4; ++mi)                                  \
          _Pragma("unroll") for (int ni = 0; ni < 4; ++ni)                              \
              acc[mi][ni] = __builtin_amdgcn_mfma_f32_16x16x32_f16(aF[mi], bF[ni],      \
                                                                   acc[mi][ni], 0, 0, 0); \
    }                                                                                   \
  }

// ---------------- GEMM + fused RoPE/scatter (produces qr, kr, vr directly) ----------
// C[8192][3072] tile: col0 spans 2 heads; wave wn owns head h0+wn, d = ni*16+m16.
// RoPE pair (d, d+32) = acc[mi][ni] / acc[mi][ni+2] — lane-local. q scaled by
// log2(e)/8. v written transposed to vr[bh][d][n] (same scatter as old rope).
__global__ __launch_bounds__(256) void gemm_qkv_rope(const __half* __restrict__ A,
                                                     const __half* __restrict__ B,
                                                     const float* __restrict__ rot,
                                                     __half* __restrict__ qr,
                                                     __half* __restrict__ kr,
                                                     __half* __restrict__ vr) {
  GEMM_CORE(A, B, 1024)

  const int s = blockIdx.x >> 3;         // 0=q, 1=k, 2=v
  const int hh = (blockIdx.x & 7) * 2 + wn;  // this wave's head
  if (s < 2) {
    const float sc = (s == 0) ? 0.18033688011112042f : 1.0f;  // log2(e)/sqrt(64)
    __half* base = (s == 0) ? qr : kr;
#pragma unroll
    for (int mi = 0; mi < 4; ++mi)
#pragma unroll
      for (int j = 0; j < 4; ++j) {
        int r = row0 + wm * 64 + mi * 16 + g * 4 + j;  // global row = b*2048+n
        int n = r & 2047;
        int bh = (r >> 11) * 16 + hh;
        __half* orow = base + ((size_t)bh * 2048 + n) * 64;
        const float* rp = rot + n * 64;
#pragma unroll
        for (int ni = 0; ni < 2; ++ni) {
          int dlo = ni * 16 + m16;
          float xlo = acc[mi][ni][j], xhi = acc[mi][ni + 2][j];
          float s0, c0, s1, c1;
          __sincosf(rp[dlo], &s0, &c0);
          __sincosf(rp[dlo + 32], &s1, &c1);
          orow[dlo]      = __float2half((xlo * c0 - xhi * s0) * sc);
          orow[dlo + 32] = __float2half((xhi * c1 + xlo * s1) * sc);
        }
      }
  } else {
#pragma unroll
    for (int mi = 0; mi < 4; ++mi)
#pragma unroll
      for (int j = 0; j < 4; ++j) {
        int r = row0 + wm * 64 + mi * 16 + g * 4 + j;
        int n = r & 2047;
        int bh = (r >> 11) * 16 + hh;
        __half* vcol = vr + ((size_t)bh * 64) * 2048 + n;
#pragma unroll
        for (int ni = 0; ni < 4; ++ni) {
          int d = ni * 16 + m16;
          vcol[(size_t)d * 2048] = __float2half(acc[mi][ni][j]);
        }
      }
  }
}

// ---------------- plain GEMM (for out-proj), f32 output ----------------
__global__ __launch_bounds__(256) void gemm_bt_f32(const __half* __restrict__ A,
                                                   const __half* __restrict__ B,
                                                   float* __restrict__ C, int N, int K) {
  GEMM_CORE(A, B, K)
#pragma unroll
  for (int mi = 0; mi < 4; ++mi)
#pragma unroll
    for (int ni = 0; ni < 4; ++ni)
#pragma unroll
      for (int j = 0; j < 4; ++j) {
        int r = row0 + wm * 64 + mi * 16 + g * 4 + j;
        int cc = col0 + wn * 64 + ni * 16 + m16;
        C[(size_t)r * N + cc] = acc[mi][ni][j];
      }
}

// ---------------- Flash attention fwd, swapped-QK 32x32 (UNCHANGED from R10/R11) --------
__global__ __launch_bounds__(256, 4) void attn_fwd(const __half* __restrict__ qr,
                                                   const __half* __restrict__ kr,
                                                   const __half* __restrict__ vr,
                                                   __half* __restrict__ out) {
  __shared__ __half K2[2 * 64 * 64];  // 16 KB
  __shared__ __half V2[2 * 64 * 64];  // 16 KB

  int bid = blockIdx.x;
  bid = (bid & 7) * 128 + (bid >> 3);  // XCD swizzle: same-head blocks share an XCD L2
  const int bh = bid >> 4;
  const int q0 = (bid & 15) * 128;
  const int tid = threadIdx.x;
  const int w = tid >> 6, l = tid & 63;
  const int q = l & 31, hi = l >> 5;
  const size_t headoff = (size_t)bh * 2048 * 64;

  // Q B-frags: Q[q0+w*32+q][c*16 + hi*8 .. +7], c=0..3 (held all block)
  f16x8 qB[4];
  {
    const __half* qp = qr + headoff + (size_t)(q0 + w * 32 + q) * 64 + hi * 8;
#pragma unroll
    for (int c = 0; c < 4; ++c) qB[c] = *(const f16x8*)(qp + c * 16);
  }

  // hoisted lane-invariant LDS read offsets
  int kf[4];  // K A-frag: byte = Kb + kvb*4096 + kf[c]   (kvb in {0,1})
#pragma unroll
  for (int c = 0; c < 4; ++c)
    kf[c] = q * 128 + 16 * (hi ^ (q & 1)) + 32 * (c ^ ((q >> 1) & 3));
  // V B-frag: byte = Vb + (vbase ^ (kvb<<6) [^32 hi16]) [+4096 for d1]
  const int vbase = q * 128 + ((hi ^ (q & 7)) << 4);

  // staging coords
  const int krow_l = l >> 3, kslot = l & 7;
  const __half* kb = kr + headoff;
  const __half* vb = vr + (size_t)bh * 64 * 2048;

  auto STAGE = [&](int buf, int kv0) {
#pragma unroll
    for (int i = 0; i < 2; ++i) {  // K [64 kv][64 d], slot ^= kv&7
      int c = w * 2 + i;
      int row = c * 8 + krow_l;
      gload_lds16(kb + (size_t)(kv0 + row) * 64 + ((kslot ^ (row & 7)) * 8),
                  (char*)K2 + buf * 8192 + c * 1024);
    }
#pragma unroll
    for (int i = 0; i < 2; ++i) {  // V [64 d][64 kv], slot ^= d&7
      int c = w * 2 + i;
      int d = c * 8 + (l >> 3);
      gload_lds16(vb + (size_t)d * 2048 + kv0 + (((l & 7) ^ (l >> 3)) * 8),
                  (char*)V2 + buf * 8192 + c * 1024);
    }
  };

  const f16x2 one2 = {(_Float16)1.f, (_Float16)1.f};
  f32x16 o0 = {}, o1 = {};  // O[q-rows][d0=q / d1=q+32]
  float mreg = -1e30f, lreg = 0.f;

  STAGE(0, 0);
  __syncthreads();

  for (int t = 0; t < 32; ++t) {
    const int buf = t & 1;
    if (t < 31) STAGE(buf ^ 1, (t + 1) * 64);  // prefetch next tile (overlaps compute)

    const char* Kb = (const char*)K2 + buf * 8192;
    const char* Vb = (const char*)V2 + buf * 8192;
#pragma unroll
    for (int kvb = 0; kvb < 2; ++kvb) {
      // ---- S^T[kv 32][q 32] = K * Q^T
      f32x16 s = {};
      __builtin_amdgcn_s_setprio(1);
#pragma unroll
      for (int c = 0; c < 4; ++c) {
        f16x8 kA = *(const f16x8*)(Kb + kvb * 4096 + kf[c]);
        s = __builtin_amdgcn_mfma_f32_32x32x16_f16(kA, qB[c], s, 0, 0, 0);
      }
      __builtin_amdgcn_s_setprio(0);

      // ---- in-register online softmax (lane owns q-col l&31, 16 kv rows)
      float mt = fmax3(s[0], s[1], s[2]);
      mt = fmax3(mt, s[3], s[4]);
      mt = fmax3(mt, s[5], s[6]);
      mt = fmax3(mt, s[7], s[8]);
      mt = fmax3(mt, s[9], s[10]);
      mt = fmax3(mt, s[11], s[12]);
      mt = fmax3(mt, s[13], s[14]);
      mt = fmaxf(mt, s[15]);
      mt = fmaxf(mt, __shfl_xor(mt, 32));
      if (__any(mt - mreg > 8.f)) {  // defer-max (T13)
        float mnew = fmaxf(mreg, mt);
        float alpha = __builtin_amdgcn_exp2f(mreg - mnew);
        lreg *= alpha;
        o0 *= alpha;
        o1 *= alpha;
        mreg = mnew;
      }
      uint32_t W[8];
      float rs = 0.f;
#pragma unroll
      for (int i2 = 0; i2 < 8; ++i2) {  // exp2 + pack + fused row-sum (fdot2)
        float e0 = __builtin_amdgcn_exp2f(s[2 * i2] - mreg);
        float e1 = __builtin_amdgcn_exp2f(s[2 * i2 + 1] - mreg);
        W[i2] = cvtpk(e0, e1);
        rs = dot2acc(W[i2], one2, rs);
      }
      rs += __shfl_xor(rs, 32);
      lreg += rs;

      // ---- P-frag redistribution: 4 permlane32_swap (proven)
      plswap(W[0], W[2]);
      plswap(W[1], W[3]);
      plswap(W[4], W[6]);
      plswap(W[5], W[7]);
      u32x4 f0 = {W[0], W[1], W[2], W[3]};
      u32x4 f1 = {W[4], W[5], W[6], W[7]};
      f16x8 pA0 = __builtin_bit_cast(f16x8, f0);  // kv kvb*32 + 0..15
      f16x8 pA1 = __builtin_bit_cast(f16x8, f1);  // kv kvb*32 + 16..31

      // ---- PV: O += P * V   (V reads from 128B-row layout)
      const int vx = vbase ^ (kvb << 6);   // kv lo-16 slot
      const int vx2 = vx ^ 32;             // kv hi-16 slot
      f16x8 v00 = *(const f16x8*)(Vb + vx);
      f16x8 v01 = *(const f16x8*)(Vb + vx + 4096);
      f16x8 v10 = *(const f16x8*)(Vb + vx2);
      f16x8 v11 = *(const f16x8*)(Vb + vx2 + 4096);
      __builtin_amdgcn_s_setprio(1);
      o0 = __builtin_amdgcn_mfma_f32_32x32x16_f16(pA0, v00, o0, 0, 0, 0);
      o1 = __builtin_amdgcn_mfma_f32_32x32x16_f16(pA0, v01, o1, 0, 0, 0);
      o0 = __builtin_amdgcn_mfma_f32_32x32x16_f16(pA1, v10, o0, 0, 0, 0);
      o1 = __builtin_amdgcn_mfma_f32_32x32x16_f16(pA1, v11, o1, 0, 0, 0);
      __builtin_amdgcn_s_setprio(0);
    }

    __syncthreads();  // fence + barrier + counter drain: next tile fully in LDS
  }

  // ---- epilogue: O reg r holds q-row (r&3)+8*(r>>2)+4*hi, d-col q (+0/32)
  const int b = bh >> 4, hh = bh & 15;
  float invl = 1.0f / lreg;
#pragma unroll
  for (int r = 0; r < 16; ++r) {
    int qrow = (r & 3) + 8 * (r >> 2) + 4 * hi;
    float inv = __shfl(invl, qrow);
    __half* orow = out + (size_t)(b * 2048 + q0 + w * 32 + qrow) * 1024 + hh * 64;
    orow[q] = __float2half(o0[r] * inv);
    orow[32 + q] = __float2half(o1[r] * inv);
  }
}

// ---------------- launch ----------------
extern "C" void kernel_launch(void* const* d_in, const int* in_sizes, int n_in,
                              void* d_out, int out_size, void* d_ws, size_t ws_size,
                              hipStream_t stream) {
  const float* x    = (const float*)d_in[0];  // [4,2048,1024]
  const float* rot  = (const float*)d_in[1];  // [2048,64]
  const float* wqkv = (const float*)d_in[2];  // [3072,1024]
  const float* wout = (const float*)d_in[3];  // [1024,1024]
  float* out = (float*)d_out;
  char* ws = (char*)d_ws;

  __half* xb    = (__half*)(ws + 0);               // 16 MB (A input, live through gemm1)
  __half* wqkvb = (__half*)(ws + (16ull << 20));   // 6 MB
  __half* woutb = (__half*)(ws + (22ull << 20));   // 2 MB
  __half* qr    = (__half*)(ws + (24ull << 20));   // 16 MB (own slot — must NOT alias xb)
  __half* ao    = (__half*)(ws + (40ull << 20));   // 16 MB
  __half* kr    = (__half*)(ws + (72ull << 20));   // 16 MB
  __half* vr    = (__half*)(ws + (88ull << 20));   // 16 MB (TRANSPOSED [bh][d][n])

  cvt_f32_f16<<<4096, 256, 0, stream>>>(x, xb, 1048576);
  cvt_f32_f16<<<1536, 256, 0, stream>>>(wqkv, wqkvb, 393216);
  cvt_f32_f16<<<512, 256, 0, stream>>>(wout, woutb, 131072);
  // fused: qkv-proj + RoPE + head-scatter -> qr, kr, vr (no qkv intermediate)
  gemm_qkv_rope<<<dim3(24, 64), 256, 0, stream>>>(xb, wqkvb, rot, qr, kr, vr);
  attn_fwd<<<1024, 256, 0, stream>>>(qr, kr, vr, ao);
  // out = ao @ woutb^T   [8192,1024] f32
  gemm_bt_f32<<<dim3(8, 64), 256, 0, stream>>>(ao, woutb, out, 1024, 1024);
}